// Round 2
// baseline (131.169 us; speedup 1.0000x reference)
//
#include <hip/hip_runtime.h>

#define NPART 500000
#define MPART 450000
#define NBXC 1024
#define NBYC 1024
#define KWIN 8
#define TILE 16
#define NTX 64
#define NTY 64
#define NTILES (NTX * NTY)

// ---------------------------------------------------------------------------
// Kernel A: velocity field + per-block partial energy sums.
// ---------------------------------------------------------------------------
__global__ __launch_bounds__(256) void field_kernel(const float* __restrict__ pot,
                                                    const float* __restrict__ rho,
                                                    float2* __restrict__ v,
                                                    float* __restrict__ partials) {
    const int idx = blockIdx.x * 256 + threadIdx.x;
    const int i = idx >> 10;
    const int j = idx & 1023;

    float a, b, scale;
    if (i == 0)            { a = pot[1 * NBYC + j];        b = pot[0 * NBYC + j];        scale = 1.0f; }
    else if (i == NBXC - 1){ a = pot[(NBXC-1) * NBYC + j]; b = pot[(NBXC-2) * NBYC + j]; scale = 1.0f; }
    else                   { a = pot[(i+1) * NBYC + j];    b = pot[(i-1) * NBYC + j];    scale = 0.5f; }
    const float vx = -(a - b) * scale;

    if (j == 0)            { a = pot[i * NBYC + 1];        b = pot[i * NBYC + 0];        scale = 1.0f; }
    else if (j == NBYC - 1){ a = pot[i * NBYC + NBYC-1];   b = pot[i * NBYC + NBYC-2];   scale = 1.0f; }
    else                   { a = pot[i * NBYC + j + 1];    b = pot[i * NBYC + j - 1];    scale = 0.5f; }
    const float vy = -(a - b) * scale;

    v[idx] = make_float2(vx, vy);

    float e = rho[idx] * (vx * vx + vy * vy);
    #pragma unroll
    for (int off = 32; off > 0; off >>= 1) e += __shfl_down(e, off, 64);
    __shared__ float smem[4];
    const int lane = threadIdx.x & 63;
    const int wid  = threadIdx.x >> 6;
    if (lane == 0) smem[wid] = e;
    __syncthreads();
    if (threadIdx.x == 0) partials[blockIdx.x] = (smem[0] + smem[1]) + (smem[2] + smem[3]);
}

// ---------------------------------------------------------------------------
// Kernel B: deterministic reduction of 4096 partials -> energy scalar.
// ---------------------------------------------------------------------------
__global__ __launch_bounds__(1024) void reduce_kernel(const float* __restrict__ partials,
                                                      float* __restrict__ out) {
    const int t = threadIdx.x;
    float e = (partials[t] + partials[t + 1024]) + (partials[t + 2048] + partials[t + 3072]);
    #pragma unroll
    for (int off = 32; off > 0; off >>= 1) e += __shfl_down(e, off, 64);
    __shared__ float smem[16];
    const int lane = t & 63;
    const int wid  = t >> 6;
    if (lane == 0) smem[wid] = e;
    __syncthreads();
    if (t == 0) {
        float s = 0.0f;
        #pragma unroll
        for (int k = 0; k < 16; ++k) s += smem[k];
        out[0] = 0.5f * s;
    }
}

// ---------------------------------------------------------------------------
// Binning pass 1: histogram particles into 64x64 tiles (16x16 cells each).
// ---------------------------------------------------------------------------
__device__ __forceinline__ int tile_of(float px, float py) {
    int tx = min(max((int)(px * (1.0f / TILE)), 0), NTX - 1);
    int ty = min(max((int)(py * (1.0f / TILE)), 0), NTY - 1);
    return tx * NTY + ty;
}

__global__ __launch_bounds__(256) void count_kernel(const float* __restrict__ pos,
                                                    int* __restrict__ counts) {
    const int i = blockIdx.x * 256 + threadIdx.x;
    if (i >= MPART) return;
    atomicAdd(&counts[tile_of(pos[i], pos[NPART + i])], 1);
}

// ---------------------------------------------------------------------------
// Binning pass 2: exclusive scan of 4096 counts using one wave (64 x 64).
// ---------------------------------------------------------------------------
__global__ __launch_bounds__(64) void scan_kernel(const int* __restrict__ counts,
                                                  int* __restrict__ offs) {
    const int t = threadIdx.x;
    int sum = 0;
    #pragma unroll 4
    for (int k = 0; k < 64; ++k) sum += counts[t * 64 + k];
    int x = sum;
    #pragma unroll
    for (int off = 1; off < 64; off <<= 1) {
        int y = __shfl_up(x, off, 64);
        if (t >= off) x += y;
    }
    int run = x - sum;   // exclusive prefix of this thread's chunk
    for (int k = 0; k < 64; ++k) {
        offs[t * 64 + k] = run;
        run += counts[t * 64 + k];
    }
}

// ---------------------------------------------------------------------------
// Binning pass 3: scatter particle data into bin order (coalesced reads,
// random writes absorbed by L2).
// ---------------------------------------------------------------------------
__global__ __launch_bounds__(256) void scatter_kernel(const float* __restrict__ pos,
                                                      const float* __restrict__ nsx,
                                                      const float* __restrict__ nsy,
                                                      int* __restrict__ offs,
                                                      int* __restrict__ perm,
                                                      float* __restrict__ pxb,
                                                      float* __restrict__ pyb,
                                                      float* __restrict__ wb,
                                                      float* __restrict__ hb) {
    const int i = blockIdx.x * 256 + threadIdx.x;
    if (i >= MPART) return;
    const float px = pos[i];
    const float py = pos[NPART + i];
    const int slot = atomicAdd(&offs[tile_of(px, py)], 1);
    perm[slot] = i;
    pxb[slot] = px;
    pyb[slot] = py;
    wb[slot]  = nsx[i];
    hb[slot]  = nsy[i];
}

// ---------------------------------------------------------------------------
// Per-particle gradient, bin-ordered, with bijective XCD-contiguous swizzle.
// ---------------------------------------------------------------------------
__device__ __forceinline__ void particle_body(int i, float px, float py, float w, float h,
                                              const float2* __restrict__ v,
                                              float* __restrict__ out) {
    float gpx, gpy;
    const bool large = (w >= 1.0f) || (h >= 1.0f);
    if (!large) {
        int ix = min(max((int)floorf(px), 0), NBXC - 1);
        int iy = min(max((int)floorf(py), 0), NBYC - 1);
        const float wx = fminf(fmaxf(px - (float)ix, 0.0f), 1.0f);
        const float wy = fminf(fmaxf(py - (float)iy, 0.0f), 1.0f);
        const int ix1 = min(ix + 1, NBXC - 1);
        const int iy1 = min(iy + 1, NBYC - 1);
        const float2 f00 = v[ix  * NBYC + iy ];
        const float2 f10 = v[ix1 * NBYC + iy ];
        const float2 f01 = v[ix  * NBYC + iy1];
        const float2 f11 = v[ix1 * NBYC + iy1];
        const float w00 = (1.0f - wx) * (1.0f - wy);
        const float w10 = wx * (1.0f - wy);
        const float w01 = (1.0f - wx) * wy;
        const float w11 = wx * wy;
        gpx = w00 * f00.x + w10 * f10.x + w01 * f01.x + w11 * f11.x;
        gpy = w00 * f00.y + w10 * f10.y + w01 * f01.y + w11 * f11.y;
    } else {
        const float lx = px - 0.5f * w, rx = px + 0.5f * w;
        const float ly = py - 0.5f * h, ry = py + 0.5f * h;
        const int bminx = min(max((int)floorf(lx), 0), NBXC - 1);
        const int bmaxx = min(max((int)floorf(rx), 0), NBXC - 1);
        const int bminy = min(max((int)floorf(ly), 0), NBYC - 1);
        const int bmaxy = min(max((int)floorf(ry), 0), NBYC - 1);

        float oy[KWIN];
        int   byi[KWIN];
        #pragma unroll
        for (int k = 0; k < KWIN; ++k) {
            const int b = bminy + k;
            const float bl = (float)b;
            float ov = fminf(ry, bl + 1.0f) - fmaxf(ly, bl);
            ov = (b <= bmaxy && ov > 0.0f) ? ov : 0.0f;
            oy[k]  = ov;
            byi[k] = min(b, NBYC - 1);
        }

        float afx = 0.0f, afy = 0.0f;
        #pragma unroll
        for (int kx = 0; kx < KWIN; ++kx) {
            const int b = bminx + kx;
            const float bl = (float)b;
            float ov = fminf(rx, bl + 1.0f) - fmaxf(lx, bl);
            ov = (b <= bmaxx && ov > 0.0f) ? ov : 0.0f;
            if (ov == 0.0f) continue;
            const int bx = min(b, NBXC - 1);
            const float2* row = v + bx * NBYC;
            float sx = 0.0f, sy = 0.0f;
            #pragma unroll
            for (int ky = 0; ky < KWIN; ++ky) {
                const float o = oy[ky];
                if (o == 0.0f) continue;
                const float2 f = row[byi[ky]];
                sx += f.x * o;
                sy += f.y * o;
            }
            afx += sx * ov;
            afy += sy * ov;
        }
        const float inv = 1.0f / fmaxf(w * h, 1e-30f);
        gpx = afx * inv;
        gpy = afy * inv;
    }
    out[1 + i]         = gpx;
    out[1 + NPART + i] = gpy;
}

__global__ __launch_bounds__(256) void particle_binned_kernel(const int* __restrict__ perm,
                                                              const float* __restrict__ pxb,
                                                              const float* __restrict__ pyb,
                                                              const float* __restrict__ wb,
                                                              const float* __restrict__ hb,
                                                              const float2* __restrict__ v,
                                                              float* __restrict__ out) {
    // bijective XCD swizzle: each XCD gets a contiguous chunk of bin-ordered blocks
    const int nwg = gridDim.x;
    const int b = blockIdx.x;
    const int q = nwg >> 3, r = nwg & 7;
    const int xcd = b & 7, k = b >> 3;
    const int sb = (xcd < r ? xcd * (q + 1) : r * (q + 1) + (xcd - r) * q) + k;
    const int j = sb * 256 + threadIdx.x;
    if (j >= MPART) return;
    particle_body(perm[j], pxb[j], pyb[j], wb[j], hb[j], v, out);
}

// fallback (ws too small): direct, unbinned
__global__ __launch_bounds__(256) void particle_direct_kernel(const float* __restrict__ pos,
                                                              const float* __restrict__ nsx,
                                                              const float* __restrict__ nsy,
                                                              const float2* __restrict__ v,
                                                              float* __restrict__ out) {
    const int i = blockIdx.x * 256 + threadIdx.x;
    if (i >= MPART) return;
    particle_body(i, pos[i], pos[NPART + i], nsx[i], nsy[i], v, out);
}

extern "C" void kernel_launch(void* const* d_in, const int* in_sizes, int n_in,
                              void* d_out, int out_size, void* d_ws, size_t ws_size,
                              hipStream_t stream) {
    const float* pos = (const float*)d_in[0];
    const float* pot = (const float*)d_in[1];
    const float* rho = (const float*)d_in[2];
    const float* nsx = (const float*)d_in[3];
    const float* nsy = (const float*)d_in[4];
    float* out = (float*)d_out;

    char* ws = (char*)d_ws;
    size_t off = 0;
    float2* v = (float2*)(ws + off);        off += (size_t)NBXC * NBYC * sizeof(float2); // 8 MB
    float* partials = (float*)(ws + off);   off += 4096 * sizeof(float);
    int* counts = (int*)(ws + off);         off += NTILES * sizeof(int);
    int* offs = (int*)(ws + off);           off += NTILES * sizeof(int);
    const size_t MPAD = 1800192;            // 450000*4 rounded to 256B
    int* perm = (int*)(ws + off);           off += MPAD;
    float* pxb = (float*)(ws + off);        off += MPAD;
    float* pyb = (float*)(ws + off);        off += MPAD;
    float* wbp = (float*)(ws + off);        off += MPAD;
    float* hbp = (float*)(ws + off);        off += MPAD;
    const size_t needed = off;

    // zero the untouched grad regions [M:N) and [N+M:2N)
    hipMemsetAsync(out + 1 + MPART,         0, (size_t)(NPART - MPART) * sizeof(float), stream);
    hipMemsetAsync(out + 1 + NPART + MPART, 0, (size_t)(NPART - MPART) * sizeof(float), stream);

    field_kernel<<<(NBXC * NBYC) / 256, 256, 0, stream>>>(pot, rho, v, partials);
    reduce_kernel<<<1, 1024, 0, stream>>>(partials, out);

    const int nwg = (MPART + 255) / 256;
    if (ws_size >= needed) {
        hipMemsetAsync(counts, 0, NTILES * sizeof(int), stream);
        count_kernel<<<nwg, 256, 0, stream>>>(pos, counts);
        scan_kernel<<<1, 64, 0, stream>>>(counts, offs);
        scatter_kernel<<<nwg, 256, 0, stream>>>(pos, nsx, nsy, offs, perm, pxb, pyb, wbp, hbp);
        particle_binned_kernel<<<nwg, 256, 0, stream>>>(perm, pxb, pyb, wbp, hbp, v, out);
    } else {
        particle_direct_kernel<<<nwg, 256, 0, stream>>>(pos, nsx, nsy, v, out);
    }
}

// Round 3
// 51.779 us; speedup vs baseline: 2.5332x; 2.5332x over previous
//
#include <hip/hip_runtime.h>
#include <hip/hip_fp16.h>

#define NPART 500000
#define MPART 450000
#define NBXC 1024
#define NBYC 1024
#define KWIN 8

// ---------------------------------------------------------------------------
// Kernel A: velocity field from potential. Energy partials in f32; field
// stored as __half2 {vx,vy} (4 MB total -> fits each XCD's 4 MB L2, so the
// particle kernel's random gathers become L2 hits).
// ---------------------------------------------------------------------------
__global__ __launch_bounds__(256) void field_kernel(const float* __restrict__ pot,
                                                    const float* __restrict__ rho,
                                                    __half2* __restrict__ v,
                                                    float* __restrict__ partials) {
    const int idx = blockIdx.x * 256 + threadIdx.x;
    const int i = idx >> 10;
    const int j = idx & 1023;

    float a, b, scale;
    if (i == 0)            { a = pot[1 * NBYC + j];        b = pot[0 * NBYC + j];        scale = 1.0f; }
    else if (i == NBXC - 1){ a = pot[(NBXC-1) * NBYC + j]; b = pot[(NBXC-2) * NBYC + j]; scale = 1.0f; }
    else                   { a = pot[(i+1) * NBYC + j];    b = pot[(i-1) * NBYC + j];    scale = 0.5f; }
    const float vx = -(a - b) * scale;

    if (j == 0)            { a = pot[i * NBYC + 1];        b = pot[i * NBYC + 0];        scale = 1.0f; }
    else if (j == NBYC - 1){ a = pot[i * NBYC + NBYC-1];   b = pot[i * NBYC + NBYC-2];   scale = 1.0f; }
    else                   { a = pot[i * NBYC + j + 1];    b = pot[i * NBYC + j - 1];    scale = 0.5f; }
    const float vy = -(a - b) * scale;

    v[idx] = __floats2half2_rn(vx, vy);

    float e = rho[idx] * (vx * vx + vy * vy);
    #pragma unroll
    for (int off = 32; off > 0; off >>= 1) e += __shfl_down(e, off, 64);
    __shared__ float smem[4];
    const int lane = threadIdx.x & 63;
    const int wid  = threadIdx.x >> 6;
    if (lane == 0) smem[wid] = e;
    __syncthreads();
    if (threadIdx.x == 0) partials[blockIdx.x] = (smem[0] + smem[1]) + (smem[2] + smem[3]);
}

// ---------------------------------------------------------------------------
// Kernel B: deterministic reduction of 4096 partials -> energy scalar.
// ---------------------------------------------------------------------------
__global__ __launch_bounds__(1024) void reduce_kernel(const float* __restrict__ partials,
                                                      float* __restrict__ out) {
    const int t = threadIdx.x;
    float e = (partials[t] + partials[t + 1024]) + (partials[t + 2048] + partials[t + 3072]);
    #pragma unroll
    for (int off = 32; off > 0; off >>= 1) e += __shfl_down(e, off, 64);
    __shared__ float smem[16];
    const int lane = t & 63;
    const int wid  = t >> 6;
    if (lane == 0) smem[wid] = e;
    __syncthreads();
    if (t == 0) {
        float s = 0.0f;
        #pragma unroll
        for (int k = 0; k < 16; ++k) s += smem[k];
        out[0] = 0.5f * s;
    }
}

// ---------------------------------------------------------------------------
// Kernel C: per-particle gradient. Grid covers N so threads in [M,N) zero the
// tail regions (replaces hipMemsetAsync). Large/small branch so ~2% small
// particles do 4 gathers, large ones do the overlap window only.
// ---------------------------------------------------------------------------
__global__ __launch_bounds__(256) void particle_kernel(const float* __restrict__ pos,
                                                       const float* __restrict__ nsx,
                                                       const float* __restrict__ nsy,
                                                       const __half2* __restrict__ v,
                                                       float* __restrict__ out) {
    const int i = blockIdx.x * 256 + threadIdx.x;
    if (i >= NPART) return;
    if (i >= MPART) {                      // zero the pad regions [M:N), [N+M:2N)
        out[1 + i]         = 0.0f;
        out[1 + NPART + i] = 0.0f;
        return;
    }

    const float px = pos[i];
    const float py = pos[NPART + i];
    const float w  = nsx[i];
    const float h  = nsy[i];

    float gpx, gpy;
    const bool large = (w >= 1.0f) || (h >= 1.0f);
    if (!large) {
        int ix = min(max((int)floorf(px), 0), NBXC - 1);
        int iy = min(max((int)floorf(py), 0), NBYC - 1);
        const float wx = fminf(fmaxf(px - (float)ix, 0.0f), 1.0f);
        const float wy = fminf(fmaxf(py - (float)iy, 0.0f), 1.0f);
        const int ix1 = min(ix + 1, NBXC - 1);
        const int iy1 = min(iy + 1, NBYC - 1);
        const float2 f00 = __half22float2(v[ix  * NBYC + iy ]);
        const float2 f10 = __half22float2(v[ix1 * NBYC + iy ]);
        const float2 f01 = __half22float2(v[ix  * NBYC + iy1]);
        const float2 f11 = __half22float2(v[ix1 * NBYC + iy1]);
        const float w00 = (1.0f - wx) * (1.0f - wy);
        const float w10 = wx * (1.0f - wy);
        const float w01 = (1.0f - wx) * wy;
        const float w11 = wx * wy;
        gpx = w00 * f00.x + w10 * f10.x + w01 * f01.x + w11 * f11.x;
        gpy = w00 * f00.y + w10 * f10.y + w01 * f01.y + w11 * f11.y;
    } else {
        const float lx = px - 0.5f * w, rx = px + 0.5f * w;
        const float ly = py - 0.5f * h, ry = py + 0.5f * h;
        const int bminx = min(max((int)floorf(lx), 0), NBXC - 1);
        const int bmaxx = min(max((int)floorf(rx), 0), NBXC - 1);
        const int bminy = min(max((int)floorf(ly), 0), NBYC - 1);
        const int bmaxy = min(max((int)floorf(ry), 0), NBYC - 1);

        float oy[KWIN];
        int   byi[KWIN];
        #pragma unroll
        for (int k = 0; k < KWIN; ++k) {
            const int b = bminy + k;
            const float bl = (float)b;
            float ov = fminf(ry, bl + 1.0f) - fmaxf(ly, bl);
            ov = (b <= bmaxy && ov > 0.0f) ? ov : 0.0f;
            oy[k]  = ov;
            byi[k] = min(b, NBYC - 1);
        }

        float afx = 0.0f, afy = 0.0f;
        #pragma unroll
        for (int kx = 0; kx < KWIN; ++kx) {
            const int b = bminx + kx;
            const float bl = (float)b;
            float ov = fminf(rx, bl + 1.0f) - fmaxf(lx, bl);
            ov = (b <= bmaxx && ov > 0.0f) ? ov : 0.0f;
            if (ov == 0.0f) continue;
            const int bx = min(b, NBXC - 1);
            const __half2* row = v + bx * NBYC;
            float sx = 0.0f, sy = 0.0f;
            #pragma unroll
            for (int ky = 0; ky < KWIN; ++ky) {
                const float o = oy[ky];
                if (o == 0.0f) continue;
                const float2 f = __half22float2(row[byi[ky]]);
                sx += f.x * o;
                sy += f.y * o;
            }
            afx += sx * ov;
            afy += sy * ov;
        }
        const float inv = 1.0f / fmaxf(w * h, 1e-30f);
        gpx = afx * inv;
        gpy = afy * inv;
    }
    out[1 + i]         = gpx;
    out[1 + NPART + i] = gpy;
}

extern "C" void kernel_launch(void* const* d_in, const int* in_sizes, int n_in,
                              void* d_out, int out_size, void* d_ws, size_t ws_size,
                              hipStream_t stream) {
    const float* pos = (const float*)d_in[0];
    const float* pot = (const float*)d_in[1];
    const float* rho = (const float*)d_in[2];
    const float* nsx = (const float*)d_in[3];
    const float* nsy = (const float*)d_in[4];
    float* out = (float*)d_out;

    __half2* v      = (__half2*)d_ws;                                     // 1024*1024*4 B = 4 MB
    float* partials = (float*)((char*)d_ws + (size_t)NBXC * NBYC * sizeof(__half2));

    field_kernel<<<(NBXC * NBYC) / 256, 256, 0, stream>>>(pot, rho, v, partials);
    reduce_kernel<<<1, 1024, 0, stream>>>(partials, out);
    particle_kernel<<<(NPART + 255) / 256, 256, 0, stream>>>(pos, nsx, nsy, v, out);
}

// Round 4
// 33.647 us; speedup vs baseline: 3.8984x; 1.5389x over previous
//
#include <hip/hip_runtime.h>
#include <hip/hip_fp16.h>

#define NPART 500000
#define MPART 450000
#define NBXC 1024
#define NBYC 1024
#define KWIN 8

// ---------------------------------------------------------------------------
// Kernel A: velocity field from potential. Energy partials in f32; field
// stored as __half2 {vx,vy} (4 MB total -> L2/L3 resident for the gathers).
// ---------------------------------------------------------------------------
__global__ __launch_bounds__(256) void field_kernel(const float* __restrict__ pot,
                                                    const float* __restrict__ rho,
                                                    __half2* __restrict__ v,
                                                    float* __restrict__ partials) {
    const int idx = blockIdx.x * 256 + threadIdx.x;
    const int i = idx >> 10;
    const int j = idx & 1023;

    float a, b, scale;
    if (i == 0)            { a = pot[1 * NBYC + j];        b = pot[0 * NBYC + j];        scale = 1.0f; }
    else if (i == NBXC - 1){ a = pot[(NBXC-1) * NBYC + j]; b = pot[(NBXC-2) * NBYC + j]; scale = 1.0f; }
    else                   { a = pot[(i+1) * NBYC + j];    b = pot[(i-1) * NBYC + j];    scale = 0.5f; }
    const float vx = -(a - b) * scale;

    if (j == 0)            { a = pot[i * NBYC + 1];        b = pot[i * NBYC + 0];        scale = 1.0f; }
    else if (j == NBYC - 1){ a = pot[i * NBYC + NBYC-1];   b = pot[i * NBYC + NBYC-2];   scale = 1.0f; }
    else                   { a = pot[i * NBYC + j + 1];    b = pot[i * NBYC + j - 1];    scale = 0.5f; }
    const float vy = -(a - b) * scale;

    v[idx] = __floats2half2_rn(vx, vy);

    float e = rho[idx] * (vx * vx + vy * vy);
    #pragma unroll
    for (int off = 32; off > 0; off >>= 1) e += __shfl_down(e, off, 64);
    __shared__ float smem[4];
    const int lane = threadIdx.x & 63;
    const int wid  = threadIdx.x >> 6;
    if (lane == 0) smem[wid] = e;
    __syncthreads();
    if (threadIdx.x == 0) partials[blockIdx.x] = (smem[0] + smem[1]) + (smem[2] + smem[3]);
}

// ---------------------------------------------------------------------------
// Kernel B: deterministic reduction of 4096 partials -> energy scalar.
// ---------------------------------------------------------------------------
__global__ __launch_bounds__(1024) void reduce_kernel(const float* __restrict__ partials,
                                                      float* __restrict__ out) {
    const int t = threadIdx.x;
    float e = (partials[t] + partials[t + 1024]) + (partials[t + 2048] + partials[t + 3072]);
    #pragma unroll
    for (int off = 32; off > 0; off >>= 1) e += __shfl_down(e, off, 64);
    __shared__ float smem[16];
    const int lane = t & 63;
    const int wid  = t >> 6;
    if (lane == 0) smem[wid] = e;
    __syncthreads();
    if (t == 0) {
        float s = 0.0f;
        #pragma unroll
        for (int k = 0; k < 16; ++k) s += smem[k];
        out[0] = 0.5f * s;
    }
}

// ---------------------------------------------------------------------------
// Kernel C: per-particle gradient. Window rows loaded as 3 aligned float4
// (12 half2 cells starting at bminy & ~3) -> 4x fewer VMEM instructions.
// The 12-cell range covers the reference's 8-bin window; extra cells get
// overlap weight 0 from the same formula (exact).
// ---------------------------------------------------------------------------
__global__ __launch_bounds__(256) void particle_kernel(const float* __restrict__ pos,
                                                       const float* __restrict__ nsx,
                                                       const float* __restrict__ nsy,
                                                       const __half2* __restrict__ v,
                                                       float* __restrict__ out) {
    const int i = blockIdx.x * 256 + threadIdx.x;
    if (i >= NPART) return;
    if (i >= MPART) {                      // zero the pad regions [M:N), [N+M:2N)
        out[1 + i]         = 0.0f;
        out[1 + NPART + i] = 0.0f;
        return;
    }

    const float px = pos[i];
    const float py = pos[NPART + i];
    const float w  = nsx[i];
    const float h  = nsy[i];

    float gpx, gpy;
    const bool large = (w >= 1.0f) || (h >= 1.0f);
    if (!large) {
        int ix = min(max((int)floorf(px), 0), NBXC - 1);
        int iy = min(max((int)floorf(py), 0), NBYC - 1);
        const float wx = fminf(fmaxf(px - (float)ix, 0.0f), 1.0f);
        const float wy = fminf(fmaxf(py - (float)iy, 0.0f), 1.0f);
        const int ix1 = min(ix + 1, NBXC - 1);
        const int iy1 = min(iy + 1, NBYC - 1);
        const float2 f00 = __half22float2(v[ix  * NBYC + iy ]);
        const float2 f10 = __half22float2(v[ix1 * NBYC + iy ]);
        const float2 f01 = __half22float2(v[ix  * NBYC + iy1]);
        const float2 f11 = __half22float2(v[ix1 * NBYC + iy1]);
        const float w00 = (1.0f - wx) * (1.0f - wy);
        const float w10 = wx * (1.0f - wy);
        const float w01 = (1.0f - wx) * wy;
        const float w11 = wx * wy;
        gpx = w00 * f00.x + w10 * f10.x + w01 * f01.x + w11 * f11.x;
        gpy = w00 * f00.y + w10 * f10.y + w01 * f01.y + w11 * f11.y;
    } else {
        const float lx = px - 0.5f * w, rx = px + 0.5f * w;
        const float ly = py - 0.5f * h, ry = py + 0.5f * h;
        const int bminx = min(max((int)floorf(lx), 0), NBXC - 1);
        const int bmaxx = min(max((int)floorf(rx), 0), NBXC - 1);
        const int bminy = min(max((int)floorf(ly), 0), NBYC - 1);
        const int bmaxy = min(max((int)floorf(ry), 0), NBYC - 1);
        const int by0   = bminy & ~3;      // 16B-aligned start of the y-window

        // overlap weights for the 12-cell aligned y-window (exact: cells
        // outside the true window get ov<=0 or fail b<=bmaxy -> weight 0)
        float oy[12];
        #pragma unroll
        for (int k = 0; k < 12; ++k) {
            const int b = by0 + k;
            const float bl = (float)b;
            float ov = fminf(ry, bl + 1.0f) - fmaxf(ly, bl);
            oy[k] = (b <= bmaxy && ov > 0.0f) ? ov : 0.0f;
        }

        float afx = 0.0f, afy = 0.0f;
        #pragma unroll
        for (int kx = 0; kx < KWIN; ++kx) {
            const int b = bminx + kx;
            const float bl = (float)b;
            float ov = fminf(rx, bl + 1.0f) - fmaxf(lx, bl);
            ov = (b <= bmaxx && ov > 0.0f) ? ov : 0.0f;
            if (ov == 0.0f) continue;
            const int bx = min(b, NBXC - 1);
            // 3 aligned float4 loads = 12 half2 cells (overread past the row
            // stays inside the 256MB workspace; weight 0)
            const float4* rp = reinterpret_cast<const float4*>(v + bx * NBYC + by0);
            float4 q0 = rp[0], q1 = rp[1], q2 = rp[2];
            const float* qs0 = &q0.x;
            const float* qs1 = &q1.x;
            const float* qs2 = &q2.x;
            float sx = 0.0f, sy = 0.0f;
            #pragma unroll
            for (int k = 0; k < 4; ++k) {
                const float2 f = __half22float2(__builtin_bit_cast(__half2, qs0[k]));
                sx += f.x * oy[k];
                sy += f.y * oy[k];
            }
            #pragma unroll
            for (int k = 0; k < 4; ++k) {
                const float2 f = __half22float2(__builtin_bit_cast(__half2, qs1[k]));
                sx += f.x * oy[4 + k];
                sy += f.y * oy[4 + k];
            }
            #pragma unroll
            for (int k = 0; k < 4; ++k) {
                const float2 f = __half22float2(__builtin_bit_cast(__half2, qs2[k]));
                sx += f.x * oy[8 + k];
                sy += f.y * oy[8 + k];
            }
            afx += sx * ov;
            afy += sy * ov;
        }
        const float inv = 1.0f / fmaxf(w * h, 1e-30f);
        gpx = afx * inv;
        gpy = afy * inv;
    }
    out[1 + i]         = gpx;
    out[1 + NPART + i] = gpy;
}

extern "C" void kernel_launch(void* const* d_in, const int* in_sizes, int n_in,
                              void* d_out, int out_size, void* d_ws, size_t ws_size,
                              hipStream_t stream) {
    const float* pos = (const float*)d_in[0];
    const float* pot = (const float*)d_in[1];
    const float* rho = (const float*)d_in[2];
    const float* nsx = (const float*)d_in[3];
    const float* nsy = (const float*)d_in[4];
    float* out = (float*)d_out;

    __half2* v      = (__half2*)d_ws;                                     // 4 MB
    float* partials = (float*)((char*)d_ws + (size_t)NBXC * NBYC * sizeof(__half2));

    field_kernel<<<(NBXC * NBYC) / 256, 256, 0, stream>>>(pot, rho, v, partials);
    reduce_kernel<<<1, 1024, 0, stream>>>(partials, out);
    particle_kernel<<<(NPART + 255) / 256, 256, 0, stream>>>(pos, nsx, nsy, v, out);
}